// Round 1
// baseline (289.798 us; speedup 1.0000x reference)
//
#include <hip/hip_runtime.h>

// Problem constants (from reference): B=4096, L=64, D=128, counts in [0,64].
#define DD   128
#define LLEN 64
#define TMAX 65   // table rows: count values 0..64 inclusive

// Kernel 1: build lookup table tab[a][e] = sum_d relu(a*W1[d]+b1[d]) * W2[d][e]
__global__ void build_table_kernel(const float* __restrict__ W1,
                                   const float* __restrict__ b1,
                                   const float* __restrict__ W2,
                                   float* __restrict__ tab) {
    const int a = blockIdx.x;    // 0..64
    const int e = threadIdx.x;   // 0..127
    const float fa = (float)a;
    float acc = 0.f;
#pragma unroll 8
    for (int d = 0; d < DD; ++d) {
        float h = fmaf(fa, W1[d], b1[d]);
        h = fmaxf(h, 0.f);
        acc = fmaf(h, W2[d * DD + e], acc);
    }
    tab[a * DD + e] = acc;
}

// Kernel 2: one block per batch row. Phase B: 64 lanes do the all-pairs counts
// with the reference's dict-mutation override semantics. Phase C: 256 threads
// write both 64x128 output tiles via table lookup, coalesced float4 stores.
__global__ __launch_bounds__(256) void nif_main_kernel(
    const int* __restrict__ src_id, const int* __restrict__ dst_id,
    const int* __restrict__ src_nb, const int* __restrict__ dst_nb,
    const float* __restrict__ tab, const float* __restrict__ b2,
    float* __restrict__ out, int B) {
    __shared__ int S[LLEN], Dn[LLEN];
    __shared__ int A0[LLEN], A1[LLEN], C0[LLEN], C1[LLEN];

    const int b = blockIdx.x;
    const int tid = threadIdx.x;

    if (tid < LLEN)          S[tid]         = src_nb[(size_t)b * LLEN + tid];
    else if (tid < 2 * LLEN) Dn[tid - LLEN] = dst_nb[(size_t)b * LLEN + (tid - LLEN)];
    __syncthreads();

    if (tid < LLEN) {
        const int sid = src_id[b];
        const int did = dst_id[b];
        const int vs = S[tid];
        const int vd = Dn[tid];
        int c_src = 0, c_dos = 0, c_dst = 0, c_sod = 0, cd_sid = 0, cs_did = 0;
#pragma unroll
        for (int j = 0; j < LLEN; ++j) {
            const int sj = S[j], dj = Dn[j];
            c_src  += (sj == vs);   // count of S[i] in S
            c_dos  += (dj == vs);   // count of S[i] in D
            c_dst  += (dj == vd);   // count of D[i] in D
            c_sod  += (sj == vd);   // count of D[i] in S
            cd_sid += (dj == sid);  // count of src_id in D
            cs_did += (sj == did);  // count of dst_id in S
        }
        const bool s_in_d = (cd_sid > 0);
        const bool same   = (sid == did);
        const bool c2     = (cs_did > 0) || (same && s_in_d);
        const int  v2     = (same && s_in_d) ? cd_sid : cs_did;
        A0[tid] = c_src;                                    // src_app[...,0]
        A1[tid] = (vs == did && c2) ? v2 : c_dos;           // src_app[...,1]
        C0[tid] = (vd == sid && s_in_d) ? cd_sid : c_sod;   // dst_app[...,0]
        C1[tid] = c_dst;                                    // dst_app[...,1]
    }
    __syncthreads();

    const float4* __restrict__ tab4 = (const float4*)tab;
    float4 b2v = ((const float4*)b2)[tid & 31];
    b2v.x += b2v.x; b2v.y += b2v.y; b2v.z += b2v.z; b2v.w += b2v.w;  // 2*b2

    float4* __restrict__ out4 = (float4*)out;
    const size_t src_base = (size_t)b * (LLEN * DD / 4);             // float4 units
    const size_t dst_base = src_base + (size_t)B * (LLEN * DD / 4);
    const int e4 = tid & 31;   // float4 column 0..31
    const int l0 = tid >> 5;   // row group 0..7
#pragma unroll
    for (int k = 0; k < 8; ++k) {
        const int l = l0 + 8 * k;
        const int idx4 = l * 32 + e4;  // == tid + 256*k, contiguous per wave
        const float4 t0 = tab4[A0[l] * 32 + e4];
        const float4 t1 = tab4[A1[l] * 32 + e4];
        float4 v;
        v.x = t0.x + t1.x + b2v.x;
        v.y = t0.y + t1.y + b2v.y;
        v.z = t0.z + t1.z + b2v.z;
        v.w = t0.w + t1.w + b2v.w;
        out4[src_base + idx4] = v;
        const float4 u0 = tab4[C0[l] * 32 + e4];
        const float4 u1 = tab4[C1[l] * 32 + e4];
        float4 w;
        w.x = u0.x + u1.x + b2v.x;
        w.y = u0.y + u1.y + b2v.y;
        w.z = u0.z + u1.z + b2v.z;
        w.w = u0.w + u1.w + b2v.w;
        out4[dst_base + idx4] = w;
    }
}

extern "C" void kernel_launch(void* const* d_in, const int* in_sizes, int n_in,
                              void* d_out, int out_size, void* d_ws, size_t ws_size,
                              hipStream_t stream) {
    const int*   src_id = (const int*)d_in[0];
    const int*   dst_id = (const int*)d_in[1];
    const int*   src_nb = (const int*)d_in[2];
    const int*   dst_nb = (const int*)d_in[3];
    const float* W1     = (const float*)d_in[4];
    const float* b1     = (const float*)d_in[5];
    const float* W2     = (const float*)d_in[6];
    const float* b2     = (const float*)d_in[7];
    float*       out    = (float*)d_out;
    float*       tab    = (float*)d_ws;   // 65*128 fp32 = 33280 B scratch

    const int B = in_sizes[0];

    build_table_kernel<<<TMAX, DD, 0, stream>>>(W1, b1, W2, tab);
    nif_main_kernel<<<B, 256, 0, stream>>>(src_id, dst_id, src_nb, dst_nb,
                                           tab, b2, out, B);
}

// Round 2
// 280.706 us; speedup vs baseline: 1.0324x; 1.0324x over previous
//
#include <hip/hip_runtime.h>

// B=4096, L=64, D=128, counts in [0,64].
#define DD   128
#define LLEN 64
#define TMAX 65          // table rows: count values 0..64
#define ROWS_PER_BLK 4   // one wave (64 lanes) per batch row

// Kernel 1: tab[a][e] = sum_d relu(a*W1[d]+b1[d]) * W2[d][e]
__global__ void build_table_kernel(const float* __restrict__ W1,
                                   const float* __restrict__ b1,
                                   const float* __restrict__ W2,
                                   float* __restrict__ tab) {
    const int a = blockIdx.x;    // 0..64
    const int e = threadIdx.x;   // 0..127
    const float fa = (float)a;
    float acc = 0.f;
#pragma unroll 8
    for (int d = 0; d < DD; ++d) {
        float h = fmaxf(fmaf(fa, W1[d], b1[d]), 0.f);
        acc = fmaf(h, W2[d * DD + e], acc);
    }
    tab[a * DD + e] = acc;
}

// Kernel 2: 4 batch rows per block, one wave per row. All 256 threads are
// active in both the count phase and the write phase.
__global__ __launch_bounds__(256) void nif_main_kernel(
    const int* __restrict__ src_id, const int* __restrict__ dst_id,
    const int* __restrict__ src_nb, const int* __restrict__ dst_nb,
    const float* __restrict__ tab, const float* __restrict__ b2,
    float* __restrict__ out, int B) {
    __shared__ int S[ROWS_PER_BLK][LLEN], Dn[ROWS_PER_BLK][LLEN];
    __shared__ int A0[ROWS_PER_BLK][LLEN], A1[ROWS_PER_BLK][LLEN];
    __shared__ int C0[ROWS_PER_BLK][LLEN], C1[ROWS_PER_BLK][LLEN];

    const int tid  = threadIdx.x;
    const int w    = tid >> 6;        // wave id 0..3
    const int lane = tid & 63;
    const int b    = blockIdx.x * ROWS_PER_BLK + w;   // this wave's batch row

    S[w][lane]  = src_nb[(size_t)b * LLEN + lane];
    Dn[w][lane] = dst_nb[(size_t)b * LLEN + lane];
    __syncthreads();

    {
        const int sid = src_id[b];
        const int did = dst_id[b];
        const int vs = S[w][lane];
        const int vd = Dn[w][lane];
        // row scalars via ballot: count of sid in D-row, did in S-row
        const int cd_sid = __popcll(__ballot(vd == sid));
        const int cs_did = __popcll(__ballot(vs == did));
        int c_src = 0, c_dos = 0, c_dst = 0, c_sod = 0;
#pragma unroll 8
        for (int j = 0; j < LLEN; ++j) {
            const int sj = S[w][j], dj = Dn[w][j];
            c_src += (sj == vs);   // count of S[i] in S
            c_dos += (dj == vs);   // count of S[i] in D
            c_dst += (dj == vd);   // count of D[i] in D
            c_sod += (sj == vd);   // count of D[i] in S
        }
        const bool s_in_d = (cd_sid > 0);
        const bool same   = (sid == did);
        const bool c2     = (cs_did > 0) || (same && s_in_d);
        const int  v2     = (same && s_in_d) ? cd_sid : cs_did;
        A0[w][lane] = c_src;                                  // src_app[...,0]
        A1[w][lane] = (vs == did && c2) ? v2 : c_dos;         // src_app[...,1]
        C0[w][lane] = (vd == sid && s_in_d) ? cd_sid : c_sod; // dst_app[...,0]
        C1[w][lane] = c_dst;                                  // dst_app[...,1]
    }
    __syncthreads();

    const float4* __restrict__ tab4 = (const float4*)tab;
    float4 b2v = ((const float4*)b2)[lane & 31];
    b2v.x += b2v.x; b2v.y += b2v.y; b2v.z += b2v.z; b2v.w += b2v.w;  // 2*b2

    float4* __restrict__ out4 = (float4*)out;
    const size_t src_base = (size_t)b * (LLEN * DD / 4);            // float4 units
    const size_t dst_base = src_base + (size_t)B * (LLEN * DD / 4);
    const int e4 = lane & 31;   // float4 column 0..31
    const int lh = lane >> 5;   // 0 or 1: which of the two rows this half-wave does
#pragma unroll 4
    for (int k = 0; k < 32; ++k) {
        const int l = 2 * k + lh;          // L-row 0..63
        const int idx4 = l * 32 + e4;      // contiguous 1KB per wave-iteration
        const float4 t0 = tab4[A0[w][l] * 32 + e4];
        const float4 t1 = tab4[A1[w][l] * 32 + e4];
        float4 v;
        v.x = t0.x + t1.x + b2v.x;
        v.y = t0.y + t1.y + b2v.y;
        v.z = t0.z + t1.z + b2v.z;
        v.w = t0.w + t1.w + b2v.w;
        out4[src_base + idx4] = v;
        const float4 u0 = tab4[C0[w][l] * 32 + e4];
        const float4 u1 = tab4[C1[w][l] * 32 + e4];
        float4 wv;
        wv.x = u0.x + u1.x + b2v.x;
        wv.y = u0.y + u1.y + b2v.y;
        wv.z = u0.z + u1.z + b2v.z;
        wv.w = u0.w + u1.w + b2v.w;
        out4[dst_base + idx4] = wv;
    }
}

extern "C" void kernel_launch(void* const* d_in, const int* in_sizes, int n_in,
                              void* d_out, int out_size, void* d_ws, size_t ws_size,
                              hipStream_t stream) {
    const int*   src_id = (const int*)d_in[0];
    const int*   dst_id = (const int*)d_in[1];
    const int*   src_nb = (const int*)d_in[2];
    const int*   dst_nb = (const int*)d_in[3];
    const float* W1     = (const float*)d_in[4];
    const float* b1     = (const float*)d_in[5];
    const float* W2     = (const float*)d_in[6];
    const float* b2     = (const float*)d_in[7];
    float*       out    = (float*)d_out;
    float*       tab    = (float*)d_ws;   // 65*128 fp32 = 33280 B scratch

    const int B = in_sizes[0];

    build_table_kernel<<<TMAX, DD, 0, stream>>>(W1, b1, W2, tab);
    nif_main_kernel<<<B / ROWS_PER_BLK, 256, 0, stream>>>(
        src_id, dst_id, src_nb, dst_nb, tab, b2, out, B);
}

// Round 3
// 278.498 us; speedup vs baseline: 1.0406x; 1.0079x over previous
//
#include <hip/hip_runtime.h>

// B=4096, L=64, D=128, counts in [0,64].
#define DD   128
#define LLEN 64
#define TMAX 65            // table rows: count values 0..64
#define ROWS_PER_BLK 4     // one wave (64 lanes) per batch row
#define TAB4 (TMAX * (DD / 4))   // 2080 float4 elements = 33280 B

// Kernel 1: tab[a][e] = b2[e] + sum_d relu(a*W1[d]+b1[d]) * W2[d][e]
// (b2 folded in: out = tab[A0] + tab[A1] gives ... + 2*b2 as required)
__global__ void build_table_kernel(const float* __restrict__ W1,
                                   const float* __restrict__ b1,
                                   const float* __restrict__ W2,
                                   const float* __restrict__ b2,
                                   float* __restrict__ tab) {
    const int a = blockIdx.x;    // 0..64
    const int e = threadIdx.x;   // 0..127
    const float fa = (float)a;
    float acc = b2[e];
#pragma unroll 8
    for (int d = 0; d < DD; ++d) {
        float h = fmaxf(fmaf(fa, W1[d], b1[d]), 0.f);
        acc = fmaf(h, W2[d * DD + e], acc);
    }
    tab[a * DD + e] = acc;
}

// Kernel 2: 4 batch rows per block, one wave per row. Table staged in LDS.
__global__ __launch_bounds__(256) void nif_main_kernel(
    const int* __restrict__ src_id, const int* __restrict__ dst_id,
    const int* __restrict__ src_nb, const int* __restrict__ dst_nb,
    const float* __restrict__ tab, float* __restrict__ out, int B) {
    __shared__ float4 TAB[TAB4];                      // 33280 B
    __shared__ int S[ROWS_PER_BLK][LLEN], Dn[ROWS_PER_BLK][LLEN];
    __shared__ int A0[ROWS_PER_BLK][LLEN], A1[ROWS_PER_BLK][LLEN];
    __shared__ int C0[ROWS_PER_BLK][LLEN], C1[ROWS_PER_BLK][LLEN];

    const int tid  = threadIdx.x;
    const int w    = tid >> 6;        // wave id 0..3
    const int lane = tid & 63;
    const int b    = blockIdx.x * ROWS_PER_BLK + w;   // this wave's batch row

    // Stage table into LDS (coalesced; 2080 float4 / 256 threads = 8.125 each)
    const float4* __restrict__ tabg = (const float4*)tab;
#pragma unroll
    for (int i = tid; i < TAB4; i += 256) TAB[i] = tabg[i];

    S[w][lane]  = src_nb[(size_t)b * LLEN + lane];
    Dn[w][lane] = dst_nb[(size_t)b * LLEN + lane];
    __syncthreads();

    {
        const int sid = src_id[b];
        const int did = dst_id[b];
        const int vs = S[w][lane];
        const int vd = Dn[w][lane];
        // row scalars via ballot: count of sid in D-row, did in S-row
        const int cd_sid = __popcll(__ballot(vd == sid));
        const int cs_did = __popcll(__ballot(vs == did));
        int c_src = 0, c_dos = 0, c_dst = 0, c_sod = 0;
#pragma unroll 8
        for (int j = 0; j < LLEN; ++j) {
            const int sj = S[w][j], dj = Dn[w][j];
            c_src += (sj == vs);   // count of S[i] in S
            c_dos += (dj == vs);   // count of S[i] in D
            c_dst += (dj == vd);   // count of D[i] in D
            c_sod += (sj == vd);   // count of D[i] in S
        }
        const bool s_in_d = (cd_sid > 0);
        const bool same   = (sid == did);
        const bool c2     = (cs_did > 0) || (same && s_in_d);
        const int  v2     = (same && s_in_d) ? cd_sid : cs_did;
        A0[w][lane] = c_src;                                  // src_app[...,0]
        A1[w][lane] = (vs == did && c2) ? v2 : c_dos;         // src_app[...,1]
        C0[w][lane] = (vd == sid && s_in_d) ? cd_sid : c_sod; // dst_app[...,0]
        C1[w][lane] = c_dst;                                  // dst_app[...,1]
    }
    __syncthreads();

    float4* __restrict__ out4 = (float4*)out;
    const size_t src_base = (size_t)b * (LLEN * DD / 4);            // float4 units
    const size_t dst_base = src_base + (size_t)B * (LLEN * DD / 4);
    const int e4 = lane & 31;   // float4 column 0..31
    const int lh = lane >> 5;   // which of two L-rows this half-wave handles
#pragma unroll 4
    for (int k = 0; k < 32; ++k) {
        const int l = 2 * k + lh;          // L-row 0..63
        const int idx4 = l * 32 + e4;      // contiguous 1KB per wave-iteration
        const float4 t0 = TAB[A0[w][l] * 32 + e4];
        const float4 t1 = TAB[A1[w][l] * 32 + e4];
        float4 v;
        v.x = t0.x + t1.x;
        v.y = t0.y + t1.y;
        v.z = t0.z + t1.z;
        v.w = t0.w + t1.w;
        out4[src_base + idx4] = v;
        const float4 u0 = TAB[C0[w][l] * 32 + e4];
        const float4 u1 = TAB[C1[w][l] * 32 + e4];
        float4 wv;
        wv.x = u0.x + u1.x;
        wv.y = u0.y + u1.y;
        wv.z = u0.z + u1.z;
        wv.w = u0.w + u1.w;
        out4[dst_base + idx4] = wv;
    }
}

extern "C" void kernel_launch(void* const* d_in, const int* in_sizes, int n_in,
                              void* d_out, int out_size, void* d_ws, size_t ws_size,
                              hipStream_t stream) {
    const int*   src_id = (const int*)d_in[0];
    const int*   dst_id = (const int*)d_in[1];
    const int*   src_nb = (const int*)d_in[2];
    const int*   dst_nb = (const int*)d_in[3];
    const float* W1     = (const float*)d_in[4];
    const float* b1     = (const float*)d_in[5];
    const float* W2     = (const float*)d_in[6];
    const float* b2     = (const float*)d_in[7];
    float*       out    = (float*)d_out;
    float*       tab    = (float*)d_ws;   // 65*128 fp32 = 33280 B scratch

    const int B = in_sizes[0];

    build_table_kernel<<<TMAX, DD, 0, stream>>>(W1, b1, W2, b2, tab);
    nif_main_kernel<<<B / ROWS_PER_BLK, 256, 0, stream>>>(
        src_id, dst_id, src_nb, dst_nb, tab, out, B);
}